// Round 3
// baseline (82.679 us; speedup 1.0000x reference)
//
#include <hip/hip_runtime.h>

// Problem constants (from reference setup)
constexpr int B   = 1024;
constexpr int S   = 16;
constexpr int DEG = 32;
constexpr int D   = 256;
constexpr int G   = B * S;          // 16384 groups
constexpr int D3  = 3 * D;          // 768

typedef float f32x4 __attribute__((ext_vector_type(4)));

// One 64-lane wave per group. Lane l owns float4 columns [4l, 4l+4).
// 4 waves (4 groups) per 256-thread block.
// 16 independent row loads kept in flight per wave (explicit registers) to
// cover L2-miss/L3 latency on the random gather.
__global__ __launch_bounds__(256) void mean_agg_kernel(
    const int*   __restrict__ nbr_ids,    // [N] = [G*DEG]
    const int*   __restrict__ batch_idx,  // [G]
    const int*   __restrict__ pos_idx,    // [G]
    const int*   __restrict__ s_tem,      // [B]
    const int*   __restrict__ r_tem,      // [B]
    const float* __restrict__ dt_flat,    // [G]
    const float* __restrict__ ent,        // [NUM_ENTS, D]
    const float* __restrict__ rel,        // [NUM_RELS, D]
    float*       __restrict__ out)        // [B*S*3D] followed by [B*S]
{
    const int wave = threadIdx.x >> 6;          // 0..3
    const int lane = threadIdx.x & 63;          // 0..63
    // Wave-uniform group id -> neighbor ids become scalar loads.
    const int g = __builtin_amdgcn_readfirstlane((blockIdx.x << 2) + wave);

    const int b = batch_idx[g];
    const int p = pos_idx[g];

    const int* ids = nbr_ids + g * DEG;   // SGPR base, const offsets -> s_load

#define ROW(e) (reinterpret_cast<const f32x4*>(ent + (size_t)(e) * D)[lane])

    f32x4 acc0 = {0.f, 0.f, 0.f, 0.f};
    f32x4 acc1 = {0.f, 0.f, 0.f, 0.f};
    f32x4 acc2 = {0.f, 0.f, 0.f, 0.f};
    f32x4 acc3 = {0.f, 0.f, 0.f, 0.f};

    #pragma unroll
    for (int h = 0; h < DEG; h += 16) {
        const int* q = ids + h;
        // Issue 16 independent loads before any use.
        f32x4 t0  = ROW(q[0]);
        f32x4 t1  = ROW(q[1]);
        f32x4 t2  = ROW(q[2]);
        f32x4 t3  = ROW(q[3]);
        f32x4 t4  = ROW(q[4]);
        f32x4 t5  = ROW(q[5]);
        f32x4 t6  = ROW(q[6]);
        f32x4 t7  = ROW(q[7]);
        f32x4 t8  = ROW(q[8]);
        f32x4 t9  = ROW(q[9]);
        f32x4 t10 = ROW(q[10]);
        f32x4 t11 = ROW(q[11]);
        f32x4 t12 = ROW(q[12]);
        f32x4 t13 = ROW(q[13]);
        f32x4 t14 = ROW(q[14]);
        f32x4 t15 = ROW(q[15]);
        acc0 += t0;  acc1 += t1;  acc2 += t2;  acc3 += t3;
        acc0 += t4;  acc1 += t5;  acc2 += t6;  acc3 += t7;
        acc0 += t8;  acc1 += t9;  acc2 += t10; acc3 += t11;
        acc0 += t12; acc1 += t13; acc2 += t14; acc3 += t15;
    }
    f32x4 acc = ((acc0 + acc1) + (acc2 + acc3)) * (1.0f / (float)DEG);

    float* orow = out + ((size_t)b * S + p) * D3;
    __builtin_nontemporal_store(acc, reinterpret_cast<f32x4*>(orow) + lane);

    // ---- subject entity embed ----
    const int se = s_tem[b];
    f32x4 sv = ROW(se);
    __builtin_nontemporal_store(sv, reinterpret_cast<f32x4*>(orow + D) + lane);

    // ---- relation embed ----
    const int re = r_tem[b];
    f32x4 rv = reinterpret_cast<const f32x4*>(rel + (size_t)re * D)[lane];
    __builtin_nontemporal_store(rv, reinterpret_cast<f32x4*>(orow + 2 * D) + lane);

    // ---- dt scatter ----
    if (lane == 0) {
        __builtin_nontemporal_store(dt_flat[g],
            out + (size_t)B * S * D3 + (size_t)b * S + p);
    }
#undef ROW
}

extern "C" void kernel_launch(void* const* d_in, const int* in_sizes, int n_in,
                              void* d_out, int out_size, void* d_ws, size_t ws_size,
                              hipStream_t stream) {
    const int*   nbr_ids   = (const int*)  d_in[0];
    // d_in[1] = seg_ids: implied by g*DEG layout (sorted, DEG per group) — unused
    const int*   batch_idx = (const int*)  d_in[2];
    const int*   pos_idx   = (const int*)  d_in[3];
    const int*   s_tem     = (const int*)  d_in[4];
    const int*   r_tem     = (const int*)  d_in[5];
    const float* dt_flat   = (const float*)d_in[6];
    const float* ent       = (const float*)d_in[7];
    const float* rel       = (const float*)d_in[8];
    float*       out       = (float*)d_out;

    const int blocks = G / 4;  // 4 groups (waves) per 256-thread block
    mean_agg_kernel<<<blocks, 256, 0, stream>>>(
        nbr_ids, batch_idx, pos_idx, s_tem, r_tem, dt_flat, ent, rel, out);
}